// Round 8
// baseline (1614.986 us; speedup 1.0000x reference)
//
#include <hip/hip_runtime.h>

#define EMBD 50
#define HID 50
#define BLK 256

typedef float f32x4 __attribute__((ext_vector_type(4)));
typedef short short8 __attribute__((ext_vector_type(8)));

__device__ __forceinline__ int imax(int a, int b) { return a > b ? a : b; }
__device__ __forceinline__ int imin(int a, int b) { return a < b ? a : b; }

__device__ __forceinline__ unsigned short f2bf(float f) {
    unsigned u = __float_as_uint(f);
    u += 0x7FFFu + ((u >> 16) & 1u);
    return (unsigned short)(u >> 16);
}
__device__ __forceinline__ float sigm(float x) {
    return __fdividef(1.0f, 1.0f + __expf(-x));
}
__device__ __forceinline__ float tanhfast(float x) {
    float e = __expf(2.0f * x);
    return 1.0f - __fdividef(2.0f, e + 1.0f);
}
__device__ __forceinline__ f32x4 sigm4(f32x4 x) {
    f32x4 r;
    r[0] = sigm(x[0]); r[1] = sigm(x[1]); r[2] = sigm(x[2]); r[3] = sigm(x[3]);
    return r;
}
__device__ __forceinline__ f32x4 tanh4(f32x4 x) {
    f32x4 r;
    r[0] = tanhfast(x[0]); r[1] = tanhfast(x[1]);
    r[2] = tanhfast(x[2]); r[3] = tanhfast(x[3]);
    return r;
}

// ---------------- length bucket sort ----------------
// ws ints: [0,25) counts, [25,50) bases, [50,75) cursors, [100,100+NW) perm
__global__ void zero_counts_kernel(int* ws) {
    if (threadIdx.x < 75) ws[threadIdx.x] = 0;
}
__global__ void hist_kernel(const int* __restrict__ lengths, int* ws, int nw) {
    int i = blockIdx.x * blockDim.x + threadIdx.x;
    if (i < nw) atomicAdd(&ws[lengths[i]], 1);
}
__global__ void prefix_kernel(int* ws) {
    if (threadIdx.x == 0 && blockIdx.x == 0) {
        int acc = 0;
        for (int l = 0; l <= 24; ++l) { ws[25 + l] = acc; acc += ws[l]; }
    }
}
__global__ void scatter_kernel(const int* __restrict__ lengths, int* ws, int nw) {
    int i = blockIdx.x * blockDim.x + threadIdx.x;
    if (i < nw) {
        int l = lengths[i];
        int pos = ws[25 + l] + atomicAdd(&ws[50 + l], 1);
        ws[100 + pos] = i;
    }
}

// ---------------- packing kernels ----------------
__global__ void pack_emb_kernel(const float* __restrict__ emb, unsigned short* __restrict__ embp,
                                int vocab) {
    int i = blockIdx.x * blockDim.x + threadIdx.x;
    if (i >= vocab * 64) return;
    int v = i >> 6, e = i & 63;
    float val = (e < EMBD) ? emb[v * EMBD + e] : (e == 63 ? 1.0f : 0.0f);
    embp[i] = f2bf(val);
}

// Weight A-fragments, row-permuted so feedback is lane-local (see R2 notes).
__global__ void pack_w_kernel(const float* __restrict__ Wih_f, const float* __restrict__ Whh_f,
                              const float* __restrict__ b_f,
                              const float* __restrict__ Wih_b, const float* __restrict__ Whh_b,
                              const float* __restrict__ b_b,
                              unsigned short* __restrict__ wp) {
    int tid = blockIdx.x * blockDim.x + threadIdx.x;
    if (tid >= 65536) return;
    int i    = tid & 7;
    int lane = (tid >> 3) & 63;
    int kc   = (tid >> 9) & 3;
    int gt   = (tid >> 11) & 15;
    int dir  = (tid >> 15) & 1;
    const float* Wih = dir ? Wih_b : Wih_f;
    const float* Whh = dir ? Whh_b : Whh_f;
    const float* bv  = dir ? b_b   : b_f;

    int m = lane & 15, grp = lane >> 4;
    int P = gt * 16 + m;
    int b = P >> 6, pp = P & 63;
    int tt = pp >> 4, ss = (pp >> 2) & 3, qq = pp & 3;
    int j = 32 * (qq >> 1) + 8 * ss + 2 * tt + (qq & 1);
    int kk = kc * 32 + 8 * grp + i;

    float val = 0.0f;
    if (j < HID) {
        int row = b * HID + j;
        if (kk < 64) {
            if (kk < EMBD)      val = Wih[row * EMBD + kk];
            else if (kk == 63)  val = bv[row];
        } else {
            int hk = kk - 64;
            if (hk < HID)       val = Whh[row * HID + hk];
        }
    }
    wp[tid] = f2bf(val);
}

// ---------------- main MFMA kernel ----------------
// By-value MFMA helper: no address-taking of the accumulator (keeps acc in VGPRs).
__device__ __forceinline__ f32x4 mf(const unsigned short* sWl, int gt, int kc,
                                    short8 bb, f32x4 acc) {
    const short8 aw = *(const short8*)(sWl + (gt * 4 + kc) * 512);
    return __builtin_amdgcn_mfma_f32_16x16x32_bf16(aw, bb, acc, 0, 0, 0);
}

#define MSTEP(KC, BB) \
    a0  = mf(sWl, 0,  KC, BB, a0);  a1  = mf(sWl, 1,  KC, BB, a1);  \
    a2  = mf(sWl, 2,  KC, BB, a2);  a3  = mf(sWl, 3,  KC, BB, a3);  \
    a4  = mf(sWl, 4,  KC, BB, a4);  a5  = mf(sWl, 5,  KC, BB, a5);  \
    a6  = mf(sWl, 6,  KC, BB, a6);  a7  = mf(sWl, 7,  KC, BB, a7);  \
    a8  = mf(sWl, 8,  KC, BB, a8);  a9  = mf(sWl, 9,  KC, BB, a9);  \
    a10 = mf(sWl, 10, KC, BB, a10); a11 = mf(sWl, 11, KC, BB, a11); \
    a12 = mf(sWl, 12, KC, BB, a12); a13 = mf(sWl, 13, KC, BB, a13); \
    a14 = mf(sWl, 14, KC, BB, a14); a15 = mf(sWl, 15, KC, BB, a15);

// Vector gate update: all elementwise on f32x4, no arrays, no allocas.
#define GATEV(AI, AF, AG, AO, C, H) {                       \
    f32x4 cn = sigm4(AF) * (C) + sigm4(AI) * tanh4(AG);     \
    f32x4 hn = sigm4(AO) * tanh4(cn);                       \
    (C) = upd ? cn : (C);                                   \
    (H) = upd ? hn : (H); }

__global__ __launch_bounds__(BLK, 2)
void bilstm_mfma_kernel(const int* __restrict__ chars,
                        const int* __restrict__ lengths,
                        const int* __restrict__ perm,
                        const unsigned short* __restrict__ embp,
                        const unsigned short* __restrict__ wp,
                        float* __restrict__ out, int nw, int ml)
{
    const int dir = blockIdx.y;
    __shared__ unsigned short sW[32768];   // 64 KB of A-fragments for this dir
    {
        const float4* src = (const float4*)(wp + dir * 32768);
        float4* dst = (float4*)sW;
        for (int i = threadIdx.x; i < 4096; i += BLK) dst[i] = src[i];
    }
    __syncthreads();

    const int lane = threadIdx.x & 63;
    const int wv   = threadIdx.x >> 6;
    const int wcol = lane & 15;          // word column
    const int s    = lane >> 4;          // lane group

    int gidx = (blockIdx.x * 4 + wv) * 16 + wcol;
    gidx = imin(gidx, nw - 1);
    const int word = perm[gidx];
    const int len  = lengths[word];

    int lmax = len;
    lmax = imax(lmax, __shfl_xor(lmax, 1));
    lmax = imax(lmax, __shfl_xor(lmax, 2));
    lmax = imax(lmax, __shfl_xor(lmax, 4));
    lmax = imax(lmax, __shfl_xor(lmax, 8));

    const int* charp = chars + (size_t)word * ml;
    const unsigned short* sWl = sW + lane * 8;

    const f32x4 zz = {0.0f, 0.0f, 0.0f, 0.0f};
    f32x4 c0 = zz, c1 = zz, c2 = zz, c3 = zz;   // cell state, named regs
    f32x4 h0 = zz, h1 = zz, h2 = zz, h3 = zz;   // hidden state, named regs
    short8 bh0, bh1;
#pragma unroll
    for (int i2 = 0; i2 < 8; ++i2) { bh0[i2] = 0; bh1[i2] = 0; }

    // prefetch x for t=0
    short8 cx0, cx1;
    if (lmax > 0) {
        int pos0 = dir ? imax(len - 1, 0) : 0;
        int ch = charp[pos0];
        cx0 = *(const short8*)(embp + ch * 64 + 8 * s);
        cx1 = *(const short8*)(embp + ch * 64 + 32 + 8 * s);
    }

    for (int t = 0; t < lmax; ++t) {
        f32x4 a0 = zz, a1 = zz, a2 = zz, a3 = zz,
              a4 = zz, a5 = zz, a6 = zz, a7 = zz,
              a8 = zz, a9 = zz, a10 = zz, a11 = zz,
              a12 = zz, a13 = zz, a14 = zz, a15 = zz;

        MSTEP(0, cx0)
        MSTEP(1, cx1)
        MSTEP(2, bh0)
        MSTEP(3, bh1)

        // prefetch next step's x while MFMAs retire
        int tn = (t + 1 < lmax) ? t + 1 : t;
        int posn = dir ? imax(len - 1 - tn, 0) : tn;
        int chn = charp[posn];
        short8 nx0 = *(const short8*)(embp + chn * 64 + 8 * s);
        short8 nx1 = *(const short8*)(embp + chn * 64 + 32 + 8 * s);

        const bool upd = (t < len);
        GATEV(a0, a4, a8,  a12, c0, h0)
        GATEV(a1, a5, a9,  a13, c1, h1)
        GATEV(a2, a6, a10, a14, c2, h2)
        GATEV(a3, a7, a11, a15, c3, h3)

        // repack frozen h (f32) -> bf16 B-fragments for next step (lane-local,
        // constant extracts only)
        bh0[0] = (short)f2bf(h0[0]); bh0[1] = (short)f2bf(h0[1]);
        bh0[2] = (short)f2bf(h1[0]); bh0[3] = (short)f2bf(h1[1]);
        bh0[4] = (short)f2bf(h2[0]); bh0[5] = (short)f2bf(h2[1]);
        bh0[6] = (short)f2bf(h3[0]); bh0[7] = (short)f2bf(h3[1]);
        bh1[0] = (short)f2bf(h0[2]); bh1[1] = (short)f2bf(h0[3]);
        bh1[2] = (short)f2bf(h1[2]); bh1[3] = (short)f2bf(h1[3]);
        bh1[4] = (short)f2bf(h2[2]); bh1[5] = (short)f2bf(h2[3]);
        bh1[6] = (short)f2bf(h3[2]); bh1[7] = (short)f2bf(h3[3]);

        cx0 = nx0; cx1 = nx1;
    }

    // out[j] for j = 32*(qq>>1) + 8*s + 2*tt + (qq&1), j < 50
    float* outw = out + (size_t)word * (2 * HID) + dir * HID;
#pragma unroll
    for (int tt = 0; tt < 4; ++tt) {
        f32x4 hv = (tt == 0) ? h0 : (tt == 1) ? h1 : (tt == 2) ? h2 : h3;
#pragma unroll
        for (int qq = 0; qq < 4; ++qq) {
            int j = 32 * (qq >> 1) + 8 * s + 2 * tt + (qq & 1);
            if (j < HID) outw[j] = hv[qq];
        }
    }
}

// ---------------- R1 fallback (scalar f32) ----------------
__global__ __launch_bounds__(BLK, 2)
void bilstm_fallback_kernel(const int* __restrict__ chars,
                            const int* __restrict__ lengths,
                            const float* __restrict__ emb,
                            const float* __restrict__ Wih_f, const float* __restrict__ Whh_f, const float* __restrict__ b_f,
                            const float* __restrict__ Wih_b, const float* __restrict__ Whh_b, const float* __restrict__ b_b,
                            const int* __restrict__ perm,
                            float* __restrict__ out, int nw, int ml)
{
    const int dir = blockIdx.y;
    const float* Wih = dir ? Wih_b : Wih_f;
    const float* Whh = dir ? Whh_b : Whh_f;
    const float* bv  = dir ? b_b  : b_f;
    __shared__ float4 sWU4[HID * 100];
    __shared__ float4 sB4[HID];
    {
        float* p = (float*)sWU4;
        for (int i = threadIdx.x; i < HID * 100 * 4; i += BLK) {
            int g = i & 3, r = i >> 2, j = r / 100, k = r - j * 100;
            p[i] = (k < EMBD) ? Wih[(j + g * HID) * EMBD + k]
                              : Whh[(j + g * HID) * HID + (k - EMBD)];
        }
        if (threadIdx.x < HID) {
            int j = threadIdx.x;
            sB4[j] = make_float4(bv[j], bv[j + HID], bv[j + 2*HID], bv[j + 3*HID]);
        }
    }
    __syncthreads();
    int gid = blockIdx.x * BLK + threadIdx.x;
    if (gid >= nw) return;
    int word = perm ? perm[gid] : gid;
    int len  = lengths[word];
    float h[HID], x[EMBD], c[HID], hn[HID];
#pragma unroll
    for (int j = 0; j < HID; ++j) h[j] = 0.f;
#pragma unroll 1
    for (int j = 0; j < HID; ++j) c[j] = 0.f;
    const int* wch = chars + word * ml;
    float* op = out + (size_t)word * (2 * HID) + dir * HID;
#pragma unroll 1
    for (int t = 0; t < len; ++t) {
        int pos = dir ? (len - 1 - t) : t;
        int ch = wch[pos];
        const float2* ep = (const float2*)(emb + ch * EMBD);
#pragma unroll
        for (int k = 0; k < EMBD / 2; ++k) { float2 v = ep[k]; x[2*k] = v.x; x[2*k+1] = v.y; }
#pragma unroll 1
        for (int j = 0; j < HID; ++j) {
            const float4* wpt = sWU4 + j * 100;
            float4 bb = sB4[j];
            float gi = bb.x, gf = bb.y, gg = bb.z, go = bb.w;
#pragma unroll
            for (int k = 0; k < EMBD; ++k) {
                float4 w = wpt[k]; float xv = x[k];
                gi += w.x*xv; gf += w.y*xv; gg += w.z*xv; go += w.w*xv;
            }
#pragma unroll
            for (int k = 0; k < HID; ++k) {
                float4 w = wpt[EMBD + k]; float hv = h[k];
                gi += w.x*hv; gf += w.y*hv; gg += w.z*hv; go += w.w*hv;
            }
            float cn = sigm(gf) * c[j] + sigm(gi) * tanhfast(gg);
            c[j] = cn;
            hn[j] = sigm(go) * tanhfast(cn);
        }
#pragma unroll
        for (int j = 0; j < HID; ++j) h[j] = hn[j];
    }
#pragma unroll
    for (int j = 0; j < HID / 2; ++j)
        ((float2*)op)[j] = make_float2(h[2*j], h[2*j+1]);
}

extern "C" void kernel_launch(void* const* d_in, const int* in_sizes, int n_in,
                              void* d_out, int out_size, void* d_ws, size_t ws_size,
                              hipStream_t stream) {
    const int*   chars = (const int*)  d_in[0];
    const int*   lens  = (const int*)  d_in[1];
    const float* emb   = (const float*)d_in[2];
    const float* Wih_f = (const float*)d_in[3];
    const float* Whh_f = (const float*)d_in[4];
    const float* b_f   = (const float*)d_in[5];
    const float* Wih_b = (const float*)d_in[6];
    const float* Whh_b = (const float*)d_in[7];
    const float* b_b   = (const float*)d_in[8];
    float* out = (float*)d_out;

    const int nw    = in_sizes[1];
    const int ml    = in_sizes[0] / nw;
    const int vocab = in_sizes[2] / EMBD;

    size_t sortNeed = (size_t)(100 + nw) * 4;
    size_t embOff   = (sortNeed + 255) & ~(size_t)255;
    size_t embBytes = (size_t)vocab * 64 * 2;
    size_t wOff     = (embOff + embBytes + 1023) & ~(size_t)1023;
    size_t need     = wOff + 131072;

    int* ws = (int*)d_ws;
    bool haveSort = ws_size >= sortNeed;
    if (haveSort) {
        zero_counts_kernel<<<1, 128, 0, stream>>>(ws);
        hist_kernel<<<(nw + 255) / 256, 256, 0, stream>>>(lens, ws, nw);
        prefix_kernel<<<1, 1, 0, stream>>>(ws);
        scatter_kernel<<<(nw + 255) / 256, 256, 0, stream>>>(lens, ws, nw);
    }

    if (ws_size >= need && haveSort) {
        unsigned short* embp = (unsigned short*)((char*)d_ws + embOff);
        unsigned short* wpk  = (unsigned short*)((char*)d_ws + wOff);
        pack_emb_kernel<<<(vocab * 64 + 255) / 256, 256, 0, stream>>>(emb, embp, vocab);
        pack_w_kernel<<<256, 256, 0, stream>>>(Wih_f, Whh_f, b_f, Wih_b, Whh_b, b_b, wpk);
        dim3 grid((nw + 63) / 64, 2);
        bilstm_mfma_kernel<<<grid, BLK, 0, stream>>>(chars, lens, ws + 100, embp, wpk,
                                                     out, nw, ml);
    } else {
        dim3 grid((nw + BLK - 1) / BLK, 2);
        bilstm_fallback_kernel<<<grid, BLK, 0, stream>>>(chars, lens, emb,
                                                         Wih_f, Whh_f, b_f,
                                                         Wih_b, Whh_b, b_b,
                                                         haveSort ? ws + 100 : nullptr,
                                                         out, nw, ml);
    }
}

// Round 10
// 1258.725 us; speedup vs baseline: 1.2830x; 1.2830x over previous
//
#include <hip/hip_runtime.h>

#define EMBD 50
#define HID 50
#define BLK 256

typedef float f32x4 __attribute__((ext_vector_type(4)));
typedef short short8 __attribute__((ext_vector_type(8)));

__device__ __forceinline__ int imax(int a, int b) { return a > b ? a : b; }
__device__ __forceinline__ int imin(int a, int b) { return a < b ? a : b; }

__device__ __forceinline__ unsigned short f2bf(float f) {
    unsigned u = __float_as_uint(f);
    u += 0x7FFFu + ((u >> 16) & 1u);
    return (unsigned short)(u >> 16);
}
__device__ __forceinline__ float sigm(float x) {
    return __fdividef(1.0f, 1.0f + __expf(-x));
}
__device__ __forceinline__ float tanhfast(float x) {
    float e = __expf(2.0f * x);
    return 1.0f - __fdividef(2.0f, e + 1.0f);
}
__device__ __forceinline__ f32x4 sigm4(f32x4 x) {
    f32x4 r;
    r[0] = sigm(x[0]); r[1] = sigm(x[1]); r[2] = sigm(x[2]); r[3] = sigm(x[3]);
    return r;
}
__device__ __forceinline__ f32x4 tanh4(f32x4 x) {
    f32x4 r;
    r[0] = tanhfast(x[0]); r[1] = tanhfast(x[1]);
    r[2] = tanhfast(x[2]); r[3] = tanhfast(x[3]);
    return r;
}

// ---------------- length bucket sort ----------------
// ws ints: [0,25) counts, [25,50) bases, [50,75) cursors, [100,100+NW) perm
__global__ void zero_counts_kernel(int* ws) {
    if (threadIdx.x < 75) ws[threadIdx.x] = 0;
}
__global__ void hist_kernel(const int* __restrict__ lengths, int* ws, int nw) {
    int i = blockIdx.x * blockDim.x + threadIdx.x;
    if (i < nw) atomicAdd(&ws[lengths[i]], 1);
}
__global__ void prefix_kernel(int* ws) {
    if (threadIdx.x == 0 && blockIdx.x == 0) {
        int acc = 0;
        for (int l = 0; l <= 24; ++l) { ws[25 + l] = acc; acc += ws[l]; }
    }
}
__global__ void scatter_kernel(const int* __restrict__ lengths, int* ws, int nw) {
    int i = blockIdx.x * blockDim.x + threadIdx.x;
    if (i < nw) {
        int l = lengths[i];
        int pos = ws[25 + l] + atomicAdd(&ws[50 + l], 1);
        ws[100 + pos] = i;
    }
}

// ---------------- packing kernels ----------------
__global__ void pack_emb_kernel(const float* __restrict__ emb, unsigned short* __restrict__ embp,
                                int vocab) {
    int i = blockIdx.x * blockDim.x + threadIdx.x;
    if (i >= vocab * 64) return;
    int v = i >> 6, e = i & 63;
    float val = (e < EMBD) ? emb[v * EMBD + e] : (e == 63 ? 1.0f : 0.0f);
    embp[i] = f2bf(val);
}

// Weight A-fragments, row-permuted so feedback is lane-local (see R2 notes).
__global__ void pack_w_kernel(const float* __restrict__ Wih_f, const float* __restrict__ Whh_f,
                              const float* __restrict__ b_f,
                              const float* __restrict__ Wih_b, const float* __restrict__ Whh_b,
                              const float* __restrict__ b_b,
                              unsigned short* __restrict__ wp) {
    int tid = blockIdx.x * blockDim.x + threadIdx.x;
    if (tid >= 65536) return;
    int i    = tid & 7;
    int lane = (tid >> 3) & 63;
    int kc   = (tid >> 9) & 3;
    int gt   = (tid >> 11) & 15;
    int dir  = (tid >> 15) & 1;
    const float* Wih = dir ? Wih_b : Wih_f;
    const float* Whh = dir ? Whh_b : Whh_f;
    const float* bv  = dir ? b_b   : b_f;

    int m = lane & 15, grp = lane >> 4;
    int P = gt * 16 + m;
    int b = P >> 6, pp = P & 63;
    int tt = pp >> 4, ss = (pp >> 2) & 3, qq = pp & 3;
    int j = 32 * (qq >> 1) + 8 * ss + 2 * tt + (qq & 1);
    int kk = kc * 32 + 8 * grp + i;

    float val = 0.0f;
    if (j < HID) {
        int row = b * HID + j;
        if (kk < 64) {
            if (kk < EMBD)      val = Wih[row * EMBD + kk];
            else if (kk == 63)  val = bv[row];
        } else {
            int hk = kk - 64;
            if (hk < HID)       val = Whh[row * HID + hk];
        }
    }
    wp[tid] = f2bf(val);
}

// ---------------- main MFMA kernel ----------------
// By-value MFMA helper: no address-taking of the accumulator.
__device__ __forceinline__ f32x4 mf(const unsigned short* sWl, int gt, int kc,
                                    short8 bb, f32x4 acc) {
    const short8 aw = *(const short8*)(sWl + (gt * 4 + kc) * 512);
    return __builtin_amdgcn_mfma_f32_16x16x32_bf16(aw, bb, acc, 0, 0, 0);
}

// One tt-block: 16 MFMAs (4 indep chains: i,f,g,o tiles for this tt) over the
// 4 K-chunks, then the gate nonlinearity for this tt. Retires its 4 acc regs
// immediately -> peak acc live = 16 VGPRs instead of 64.
#define TTBLOCK(TT, C, H) {                                                  \
    f32x4 aI = zz, aF = zz, aG = zz, aO = zz;                                \
    aI = mf(sWl, (TT),      0, cx0, aI); aF = mf(sWl, (TT) + 4,  0, cx0, aF);\
    aG = mf(sWl, (TT) + 8,  0, cx0, aG); aO = mf(sWl, (TT) + 12, 0, cx0, aO);\
    aI = mf(sWl, (TT),      1, cx1, aI); aF = mf(sWl, (TT) + 4,  1, cx1, aF);\
    aG = mf(sWl, (TT) + 8,  1, cx1, aG); aO = mf(sWl, (TT) + 12, 1, cx1, aO);\
    aI = mf(sWl, (TT),      2, bh0, aI); aF = mf(sWl, (TT) + 4,  2, bh0, aF);\
    aG = mf(sWl, (TT) + 8,  2, bh0, aG); aO = mf(sWl, (TT) + 12, 2, bh0, aO);\
    aI = mf(sWl, (TT),      3, bh1, aI); aF = mf(sWl, (TT) + 4,  3, bh1, aF);\
    aG = mf(sWl, (TT) + 8,  3, bh1, aG); aO = mf(sWl, (TT) + 12, 3, bh1, aO);\
    f32x4 cn = sigm4(aF) * (C) + sigm4(aI) * tanh4(aG);                      \
    f32x4 hn = sigm4(aO) * tanh4(cn);                                        \
    (C) = upd ? cn : (C);                                                    \
    (H) = upd ? hn : (H); }

__global__ __launch_bounds__(BLK, 2)
void bilstm_mfma_kernel(const int* __restrict__ chars,
                        const int* __restrict__ lengths,
                        const int* __restrict__ perm,
                        const unsigned short* __restrict__ embp,
                        const unsigned short* __restrict__ wp,
                        float* __restrict__ out, int nw, int ml)
{
    const int dir = blockIdx.y;
    __shared__ unsigned short sW[32768];   // 64 KB of A-fragments for this dir
    {
        const float4* src = (const float4*)(wp + dir * 32768);
        float4* dst = (float4*)sW;
        for (int i = threadIdx.x; i < 4096; i += BLK) dst[i] = src[i];
    }
    __syncthreads();

    const int lane = threadIdx.x & 63;
    const int wv   = threadIdx.x >> 6;
    const int wcol = lane & 15;          // word column
    const int s    = lane >> 4;          // lane group

    int gidx = (blockIdx.x * 4 + wv) * 16 + wcol;
    gidx = imin(gidx, nw - 1);
    const int word = perm[gidx];
    const int len  = lengths[word];

    int lmax = len;
    lmax = imax(lmax, __shfl_xor(lmax, 1));
    lmax = imax(lmax, __shfl_xor(lmax, 2));
    lmax = imax(lmax, __shfl_xor(lmax, 4));
    lmax = imax(lmax, __shfl_xor(lmax, 8));

    const int* charp = chars + (size_t)word * ml;
    const unsigned short* sWl = sW + lane * 8;

    const f32x4 zz = {0.0f, 0.0f, 0.0f, 0.0f};
    f32x4 c0 = zz, c1 = zz, c2 = zz, c3 = zz;   // cell state, named regs
    f32x4 h0 = zz, h1 = zz, h2 = zz, h3 = zz;   // hidden state, named regs
    short8 bh0, bh1;
#pragma unroll
    for (int i2 = 0; i2 < 8; ++i2) { bh0[i2] = 0; bh1[i2] = 0; }

    // prefetch x for t=0
    short8 cx0, cx1;
    if (lmax > 0) {
        int pos0 = dir ? imax(len - 1, 0) : 0;
        int ch = charp[pos0];
        cx0 = *(const short8*)(embp + ch * 64 + 8 * s);
        cx1 = *(const short8*)(embp + ch * 64 + 32 + 8 * s);
    }

    for (int t = 0; t < lmax; ++t) {
        // prefetch next step's x (latency hides under the MFMA blocks)
        int tn = (t + 1 < lmax) ? t + 1 : t;
        int posn = dir ? imax(len - 1 - tn, 0) : tn;
        int chn = charp[posn];
        short8 nx0 = *(const short8*)(embp + chn * 64 + 8 * s);
        short8 nx1 = *(const short8*)(embp + chn * 64 + 32 + 8 * s);

        const bool upd = (t < len);
        // bh0/bh1 hold PREVIOUS h throughout all four blocks; rebuilt after.
        TTBLOCK(0, c0, h0)
        TTBLOCK(1, c1, h1)
        TTBLOCK(2, c2, h2)
        TTBLOCK(3, c3, h3)

        // repack frozen h (f32) -> bf16 B-fragments for next step (lane-local,
        // constant extracts only)
        bh0[0] = (short)f2bf(h0[0]); bh0[1] = (short)f2bf(h0[1]);
        bh0[2] = (short)f2bf(h1[0]); bh0[3] = (short)f2bf(h1[1]);
        bh0[4] = (short)f2bf(h2[0]); bh0[5] = (short)f2bf(h2[1]);
        bh0[6] = (short)f2bf(h3[0]); bh0[7] = (short)f2bf(h3[1]);
        bh1[0] = (short)f2bf(h0[2]); bh1[1] = (short)f2bf(h0[3]);
        bh1[2] = (short)f2bf(h1[2]); bh1[3] = (short)f2bf(h1[3]);
        bh1[4] = (short)f2bf(h2[2]); bh1[5] = (short)f2bf(h2[3]);
        bh1[6] = (short)f2bf(h3[2]); bh1[7] = (short)f2bf(h3[3]);

        cx0 = nx0; cx1 = nx1;
    }

    // out[j] for j = 32*(qq>>1) + 8*s + 2*tt + (qq&1), j < 50
    float* outw = out + (size_t)word * (2 * HID) + dir * HID;
#pragma unroll
    for (int tt = 0; tt < 4; ++tt) {
        f32x4 hv = (tt == 0) ? h0 : (tt == 1) ? h1 : (tt == 2) ? h2 : h3;
#pragma unroll
        for (int qq = 0; qq < 4; ++qq) {
            int j = 32 * (qq >> 1) + 8 * s + 2 * tt + (qq & 1);
            if (j < HID) outw[j] = hv[qq];
        }
    }
}

// ---------------- R1 fallback (scalar f32) ----------------
__global__ __launch_bounds__(BLK, 2)
void bilstm_fallback_kernel(const int* __restrict__ chars,
                            const int* __restrict__ lengths,
                            const float* __restrict__ emb,
                            const float* __restrict__ Wih_f, const float* __restrict__ Whh_f, const float* __restrict__ b_f,
                            const float* __restrict__ Wih_b, const float* __restrict__ Whh_b, const float* __restrict__ b_b,
                            const int* __restrict__ perm,
                            float* __restrict__ out, int nw, int ml)
{
    const int dir = blockIdx.y;
    const float* Wih = dir ? Wih_b : Wih_f;
    const float* Whh = dir ? Whh_b : Whh_f;
    const float* bv  = dir ? b_b  : b_f;
    __shared__ float4 sWU4[HID * 100];
    __shared__ float4 sB4[HID];
    {
        float* p = (float*)sWU4;
        for (int i = threadIdx.x; i < HID * 100 * 4; i += BLK) {
            int g = i & 3, r = i >> 2, j = r / 100, k = r - j * 100;
            p[i] = (k < EMBD) ? Wih[(j + g * HID) * EMBD + k]
                              : Whh[(j + g * HID) * HID + (k - EMBD)];
        }
        if (threadIdx.x < HID) {
            int j = threadIdx.x;
            sB4[j] = make_float4(bv[j], bv[j + HID], bv[j + 2*HID], bv[j + 3*HID]);
        }
    }
    __syncthreads();
    int gid = blockIdx.x * BLK + threadIdx.x;
    if (gid >= nw) return;
    int word = perm ? perm[gid] : gid;
    int len  = lengths[word];
    float h[HID], x[EMBD], c[HID], hn[HID];
#pragma unroll
    for (int j = 0; j < HID; ++j) h[j] = 0.f;
#pragma unroll 1
    for (int j = 0; j < HID; ++j) c[j] = 0.f;
    const int* wch = chars + word * ml;
    float* op = out + (size_t)word * (2 * HID) + dir * HID;
#pragma unroll 1
    for (int t = 0; t < len; ++t) {
        int pos = dir ? (len - 1 - t) : t;
        int ch = wch[pos];
        const float2* ep = (const float2*)(emb + ch * EMBD);
#pragma unroll
        for (int k = 0; k < EMBD / 2; ++k) { float2 v = ep[k]; x[2*k] = v.x; x[2*k+1] = v.y; }
#pragma unroll 1
        for (int j = 0; j < HID; ++j) {
            const float4* wpt = sWU4 + j * 100;
            float4 bb = sB4[j];
            float gi = bb.x, gf = bb.y, gg = bb.z, go = bb.w;
#pragma unroll
            for (int k = 0; k < EMBD; ++k) {
                float4 w = wpt[k]; float xv = x[k];
                gi += w.x*xv; gf += w.y*xv; gg += w.z*xv; go += w.w*xv;
            }
#pragma unroll
            for (int k = 0; k < HID; ++k) {
                float4 w = wpt[EMBD + k]; float hv = h[k];
                gi += w.x*hv; gf += w.y*hv; gg += w.z*hv; go += w.w*hv;
            }
            float cn = sigm(gf) * c[j] + sigm(gi) * tanhfast(gg);
            c[j] = cn;
            hn[j] = sigm(go) * tanhfast(cn);
        }
#pragma unroll
        for (int j = 0; j < HID; ++j) h[j] = hn[j];
    }
#pragma unroll
    for (int j = 0; j < HID / 2; ++j)
        ((float2*)op)[j] = make_float2(h[2*j], h[2*j+1]);
}

extern "C" void kernel_launch(void* const* d_in, const int* in_sizes, int n_in,
                              void* d_out, int out_size, void* d_ws, size_t ws_size,
                              hipStream_t stream) {
    const int*   chars = (const int*)  d_in[0];
    const int*   lens  = (const int*)  d_in[1];
    const float* emb   = (const float*)d_in[2];
    const float* Wih_f = (const float*)d_in[3];
    const float* Whh_f = (const float*)d_in[4];
    const float* b_f   = (const float*)d_in[5];
    const float* Wih_b = (const float*)d_in[6];
    const float* Whh_b = (const float*)d_in[7];
    const float* b_b   = (const float*)d_in[8];
    float* out = (float*)d_out;

    const int nw    = in_sizes[1];
    const int ml    = in_sizes[0] / nw;
    const int vocab = in_sizes[2] / EMBD;

    size_t sortNeed = (size_t)(100 + nw) * 4;
    size_t embOff   = (sortNeed + 255) & ~(size_t)255;
    size_t embBytes = (size_t)vocab * 64 * 2;
    size_t wOff     = (embOff + embBytes + 1023) & ~(size_t)1023;
    size_t need     = wOff + 131072;

    int* ws = (int*)d_ws;
    bool haveSort = ws_size >= sortNeed;
    if (haveSort) {
        zero_counts_kernel<<<1, 128, 0, stream>>>(ws);
        hist_kernel<<<(nw + 255) / 256, 256, 0, stream>>>(lens, ws, nw);
        prefix_kernel<<<1, 1, 0, stream>>>(ws);
        scatter_kernel<<<(nw + 255) / 256, 256, 0, stream>>>(lens, ws, nw);
    }

    if (ws_size >= need && haveSort) {
        unsigned short* embp = (unsigned short*)((char*)d_ws + embOff);
        unsigned short* wpk  = (unsigned short*)((char*)d_ws + wOff);
        pack_emb_kernel<<<(vocab * 64 + 255) / 256, 256, 0, stream>>>(emb, embp, vocab);
        pack_w_kernel<<<256, 256, 0, stream>>>(Wih_f, Whh_f, b_f, Wih_b, Whh_b, b_b, wpk);
        dim3 grid((nw + 63) / 64, 2);
        bilstm_mfma_kernel<<<grid, BLK, 0, stream>>>(chars, lens, ws + 100, embp, wpk,
                                                     out, nw, ml);
    } else {
        dim3 grid((nw + BLK - 1) / BLK, 2);
        bilstm_fallback_kernel<<<grid, BLK, 0, stream>>>(chars, lens, emb,
                                                         Wih_f, Whh_f, b_f,
                                                         Wih_b, Whh_b, b_b,
                                                         haveSort ? ws + 100 : nullptr,
                                                         out, nw, ml);
    }
}

// Round 11
// 1037.719 us; speedup vs baseline: 1.5563x; 1.2130x over previous
//
#include <hip/hip_runtime.h>

#define EMBD 50
#define HID 50
#define BLK 256

typedef float f32x4 __attribute__((ext_vector_type(4)));
typedef short short8 __attribute__((ext_vector_type(8)));

__device__ __forceinline__ int imax(int a, int b) { return a > b ? a : b; }
__device__ __forceinline__ int imin(int a, int b) { return a < b ? a : b; }

__device__ __forceinline__ unsigned short f2bf(float f) {
    unsigned u = __float_as_uint(f);
    u += 0x7FFFu + ((u >> 16) & 1u);
    return (unsigned short)(u >> 16);
}
__device__ __forceinline__ float sigm(float x) {
    return __fdividef(1.0f, 1.0f + __expf(-x));
}
__device__ __forceinline__ float tanhfast(float x) {
    float e = __expf(2.0f * x);
    return 1.0f - __fdividef(2.0f, e + 1.0f);
}
__device__ __forceinline__ f32x4 sigm4(f32x4 x) {
    f32x4 r;
    r[0] = sigm(x[0]); r[1] = sigm(x[1]); r[2] = sigm(x[2]); r[3] = sigm(x[3]);
    return r;
}
__device__ __forceinline__ f32x4 tanh4(f32x4 x) {
    f32x4 r;
    r[0] = tanhfast(x[0]); r[1] = tanhfast(x[1]);
    r[2] = tanhfast(x[2]); r[3] = tanhfast(x[3]);
    return r;
}

// ---------------- length bucket sort ----------------
// ws ints: [0,25) counts, [25,50) bases, [50,75) cursors, [100,100+NW) perm
__global__ void zero_counts_kernel(int* ws) {
    if (threadIdx.x < 75) ws[threadIdx.x] = 0;
}
__global__ void hist_kernel(const int* __restrict__ lengths, int* ws, int nw) {
    int i = blockIdx.x * blockDim.x + threadIdx.x;
    if (i < nw) atomicAdd(&ws[lengths[i]], 1);
}
__global__ void prefix_kernel(int* ws) {
    if (threadIdx.x == 0 && blockIdx.x == 0) {
        int acc = 0;
        for (int l = 0; l <= 24; ++l) { ws[25 + l] = acc; acc += ws[l]; }
    }
}
__global__ void scatter_kernel(const int* __restrict__ lengths, int* ws, int nw) {
    int i = blockIdx.x * blockDim.x + threadIdx.x;
    if (i < nw) {
        int l = lengths[i];
        int pos = ws[25 + l] + atomicAdd(&ws[50 + l], 1);
        ws[100 + pos] = i;
    }
}

// ---------------- packing kernels ----------------
__global__ void pack_emb_kernel(const float* __restrict__ emb, unsigned short* __restrict__ embp,
                                int vocab) {
    int i = blockIdx.x * blockDim.x + threadIdx.x;
    if (i >= vocab * 64) return;
    int v = i >> 6, e = i & 63;
    float val = (e < EMBD) ? emb[v * EMBD + e] : (e == 63 ? 1.0f : 0.0f);
    embp[i] = f2bf(val);
}

// Weight A-fragments, row-permuted so feedback is lane-local (see R2 notes).
__global__ void pack_w_kernel(const float* __restrict__ Wih_f, const float* __restrict__ Whh_f,
                              const float* __restrict__ b_f,
                              const float* __restrict__ Wih_b, const float* __restrict__ Whh_b,
                              const float* __restrict__ b_b,
                              unsigned short* __restrict__ wp) {
    int tid = blockIdx.x * blockDim.x + threadIdx.x;
    if (tid >= 65536) return;
    int i    = tid & 7;
    int lane = (tid >> 3) & 63;
    int kc   = (tid >> 9) & 3;
    int gt   = (tid >> 11) & 15;
    int dir  = (tid >> 15) & 1;
    const float* Wih = dir ? Wih_b : Wih_f;
    const float* Whh = dir ? Whh_b : Whh_f;
    const float* bv  = dir ? b_b   : b_f;

    int m = lane & 15, grp = lane >> 4;
    int P = gt * 16 + m;
    int b = P >> 6, pp = P & 63;
    int tt = pp >> 4, ss = (pp >> 2) & 3, qq = pp & 3;
    int j = 32 * (qq >> 1) + 8 * ss + 2 * tt + (qq & 1);
    int kk = kc * 32 + 8 * grp + i;

    float val = 0.0f;
    if (j < HID) {
        int row = b * HID + j;
        if (kk < 64) {
            if (kk < EMBD)      val = Wih[row * EMBD + kk];
            else if (kk == 63)  val = bv[row];
        } else {
            int hk = kk - 64;
            if (hk < HID)       val = Whh[row * HID + hk];
        }
    }
    wp[tid] = f2bf(val);
}

// ---------------- main MFMA kernel ----------------
// By-value MFMA helper: no address-taking of the accumulator.
__device__ __forceinline__ f32x4 mf(const unsigned short* sWl, int gt, int kc,
                                    short8 bb, f32x4 acc) {
    const short8 aw = *(const short8*)(sWl + (gt * 4 + kc) * 512);
    return __builtin_amdgcn_mfma_f32_16x16x32_bf16(aw, bb, acc, 0, 0, 0);
}

// One tt-block: 16 MFMAs (4 indep chains: i,f,g,o tiles for this tt) over the
// 4 K-chunks, then the gate nonlinearity for this tt. Retires its 4 acc regs
// immediately -> peak acc live = 16 VGPRs instead of 64.
#define TTBLOCK(TT, C, H) {                                                  \
    f32x4 aI = zz, aF = zz, aG = zz, aO = zz;                                \
    aI = mf(sWl, (TT),      0, cx0, aI); aF = mf(sWl, (TT) + 4,  0, cx0, aF);\
    aG = mf(sWl, (TT) + 8,  0, cx0, aG); aO = mf(sWl, (TT) + 12, 0, cx0, aO);\
    aI = mf(sWl, (TT),      1, cx1, aI); aF = mf(sWl, (TT) + 4,  1, cx1, aF);\
    aG = mf(sWl, (TT) + 8,  1, cx1, aG); aO = mf(sWl, (TT) + 12, 1, cx1, aO);\
    aI = mf(sWl, (TT),      2, bh0, aI); aF = mf(sWl, (TT) + 4,  2, bh0, aF);\
    aG = mf(sWl, (TT) + 8,  2, bh0, aG); aO = mf(sWl, (TT) + 12, 2, bh0, aO);\
    aI = mf(sWl, (TT),      3, bh1, aI); aF = mf(sWl, (TT) + 4,  3, bh1, aF);\
    aG = mf(sWl, (TT) + 8,  3, bh1, aG); aO = mf(sWl, (TT) + 12, 3, bh1, aO);\
    f32x4 cn = sigm4(aF) * (C) + sigm4(aI) * tanh4(aG);                      \
    f32x4 hn = sigm4(aO) * tanh4(cn);                                        \
    (C) = upd ? cn : (C);                                                    \
    (H) = upd ? hn : (H); }

__global__ __launch_bounds__(BLK, 1)
void bilstm_mfma_kernel(const int* __restrict__ chars,
                        const int* __restrict__ lengths,
                        const int* __restrict__ perm,
                        const unsigned short* __restrict__ embp,
                        const unsigned short* __restrict__ wp,
                        float* __restrict__ out, int nw, int ml)
{
    const int dir = blockIdx.y;
    __shared__ unsigned short sW[32768];   // 64 KB of A-fragments for this dir
    {
        const float4* src = (const float4*)(wp + dir * 32768);
        float4* dst = (float4*)sW;
        for (int i = threadIdx.x; i < 4096; i += BLK) dst[i] = src[i];
    }
    __syncthreads();

    const int lane = threadIdx.x & 63;
    const int wv   = threadIdx.x >> 6;
    const int wcol = lane & 15;          // word column
    const int s    = lane >> 4;          // lane group

    int gidx = (blockIdx.x * 4 + wv) * 16 + wcol;
    gidx = imin(gidx, nw - 1);
    const int word = perm[gidx];
    const int len  = lengths[word];

    int lmax = len;
    lmax = imax(lmax, __shfl_xor(lmax, 1));
    lmax = imax(lmax, __shfl_xor(lmax, 2));
    lmax = imax(lmax, __shfl_xor(lmax, 4));
    lmax = imax(lmax, __shfl_xor(lmax, 8));

    const int* charp = chars + (size_t)word * ml;
    const unsigned short* sWl = sW + lane * 8;

    const f32x4 zz = {0.0f, 0.0f, 0.0f, 0.0f};
    f32x4 c0 = zz, c1 = zz, c2 = zz, c3 = zz;   // cell state, named regs
    f32x4 h0 = zz, h1 = zz, h2 = zz, h3 = zz;   // hidden state, named regs
    short8 bh0, bh1;
#pragma unroll
    for (int i2 = 0; i2 < 8; ++i2) { bh0[i2] = 0; bh1[i2] = 0; }

    // prefetch x for t=0
    short8 cx0, cx1;
    if (lmax > 0) {
        int pos0 = dir ? imax(len - 1, 0) : 0;
        int ch = charp[pos0];
        cx0 = *(const short8*)(embp + ch * 64 + 8 * s);
        cx1 = *(const short8*)(embp + ch * 64 + 32 + 8 * s);
    }

    for (int t = 0; t < lmax; ++t) {
        // prefetch next step's x (latency hides under the MFMA blocks)
        int tn = (t + 1 < lmax) ? t + 1 : t;
        int posn = dir ? imax(len - 1 - tn, 0) : tn;
        int chn = charp[posn];
        short8 nx0 = *(const short8*)(embp + chn * 64 + 8 * s);
        short8 nx1 = *(const short8*)(embp + chn * 64 + 32 + 8 * s);

        const bool upd = (t < len);
        // bh0/bh1 hold PREVIOUS h throughout all four blocks; rebuilt after.
        TTBLOCK(0, c0, h0)
        TTBLOCK(1, c1, h1)
        TTBLOCK(2, c2, h2)
        TTBLOCK(3, c3, h3)

        // repack frozen h (f32) -> bf16 B-fragments for next step (lane-local,
        // constant extracts only)
        bh0[0] = (short)f2bf(h0[0]); bh0[1] = (short)f2bf(h0[1]);
        bh0[2] = (short)f2bf(h1[0]); bh0[3] = (short)f2bf(h1[1]);
        bh0[4] = (short)f2bf(h2[0]); bh0[5] = (short)f2bf(h2[1]);
        bh0[6] = (short)f2bf(h3[0]); bh0[7] = (short)f2bf(h3[1]);
        bh1[0] = (short)f2bf(h0[2]); bh1[1] = (short)f2bf(h0[3]);
        bh1[2] = (short)f2bf(h1[2]); bh1[3] = (short)f2bf(h1[3]);
        bh1[4] = (short)f2bf(h2[2]); bh1[5] = (short)f2bf(h2[3]);
        bh1[6] = (short)f2bf(h3[2]); bh1[7] = (short)f2bf(h3[3]);

        cx0 = nx0; cx1 = nx1;
    }

    // out[j] for j = 32*(qq>>1) + 8*s + 2*tt + (qq&1), j < 50
    float* outw = out + (size_t)word * (2 * HID) + dir * HID;
#pragma unroll
    for (int tt = 0; tt < 4; ++tt) {
        f32x4 hv = (tt == 0) ? h0 : (tt == 1) ? h1 : (tt == 2) ? h2 : h3;
#pragma unroll
        for (int qq = 0; qq < 4; ++qq) {
            int j = 32 * (qq >> 1) + 8 * s + 2 * tt + (qq & 1);
            if (j < HID) outw[j] = hv[qq];
        }
    }
}

// ---------------- R1 fallback (scalar f32) ----------------
__global__ __launch_bounds__(BLK, 2)
void bilstm_fallback_kernel(const int* __restrict__ chars,
                            const int* __restrict__ lengths,
                            const float* __restrict__ emb,
                            const float* __restrict__ Wih_f, const float* __restrict__ Whh_f, const float* __restrict__ b_f,
                            const float* __restrict__ Wih_b, const float* __restrict__ Whh_b, const float* __restrict__ b_b,
                            const int* __restrict__ perm,
                            float* __restrict__ out, int nw, int ml)
{
    const int dir = blockIdx.y;
    const float* Wih = dir ? Wih_b : Wih_f;
    const float* Whh = dir ? Whh_b : Whh_f;
    const float* bv  = dir ? b_b  : b_f;
    __shared__ float4 sWU4[HID * 100];
    __shared__ float4 sB4[HID];
    {
        float* p = (float*)sWU4;
        for (int i = threadIdx.x; i < HID * 100 * 4; i += BLK) {
            int g = i & 3, r = i >> 2, j = r / 100, k = r - j * 100;
            p[i] = (k < EMBD) ? Wih[(j + g * HID) * EMBD + k]
                              : Whh[(j + g * HID) * HID + (k - EMBD)];
        }
        if (threadIdx.x < HID) {
            int j = threadIdx.x;
            sB4[j] = make_float4(bv[j], bv[j + HID], bv[j + 2*HID], bv[j + 3*HID]);
        }
    }
    __syncthreads();
    int gid = blockIdx.x * BLK + threadIdx.x;
    if (gid >= nw) return;
    int word = perm ? perm[gid] : gid;
    int len  = lengths[word];
    float h[HID], x[EMBD], c[HID], hn[HID];
#pragma unroll
    for (int j = 0; j < HID; ++j) h[j] = 0.f;
#pragma unroll 1
    for (int j = 0; j < HID; ++j) c[j] = 0.f;
    const int* wch = chars + word * ml;
    float* op = out + (size_t)word * (2 * HID) + dir * HID;
#pragma unroll 1
    for (int t = 0; t < len; ++t) {
        int pos = dir ? (len - 1 - t) : t;
        int ch = wch[pos];
        const float2* ep = (const float2*)(emb + ch * EMBD);
#pragma unroll
        for (int k = 0; k < EMBD / 2; ++k) { float2 v = ep[k]; x[2*k] = v.x; x[2*k+1] = v.y; }
#pragma unroll 1
        for (int j = 0; j < HID; ++j) {
            const float4* wpt = sWU4 + j * 100;
            float4 bb = sB4[j];
            float gi = bb.x, gf = bb.y, gg = bb.z, go = bb.w;
#pragma unroll
            for (int k = 0; k < EMBD; ++k) {
                float4 w = wpt[k]; float xv = x[k];
                gi += w.x*xv; gf += w.y*xv; gg += w.z*xv; go += w.w*xv;
            }
#pragma unroll
            for (int k = 0; k < HID; ++k) {
                float4 w = wpt[EMBD + k]; float hv = h[k];
                gi += w.x*hv; gf += w.y*hv; gg += w.z*hv; go += w.w*hv;
            }
            float cn = sigm(gf) * c[j] + sigm(gi) * tanhfast(gg);
            c[j] = cn;
            hn[j] = sigm(go) * tanhfast(cn);
        }
#pragma unroll
        for (int j = 0; j < HID; ++j) h[j] = hn[j];
    }
#pragma unroll
    for (int j = 0; j < HID / 2; ++j)
        ((float2*)op)[j] = make_float2(h[2*j], h[2*j+1]);
}

extern "C" void kernel_launch(void* const* d_in, const int* in_sizes, int n_in,
                              void* d_out, int out_size, void* d_ws, size_t ws_size,
                              hipStream_t stream) {
    const int*   chars = (const int*)  d_in[0];
    const int*   lens  = (const int*)  d_in[1];
    const float* emb   = (const float*)d_in[2];
    const float* Wih_f = (const float*)d_in[3];
    const float* Whh_f = (const float*)d_in[4];
    const float* b_f   = (const float*)d_in[5];
    const float* Wih_b = (const float*)d_in[6];
    const float* Whh_b = (const float*)d_in[7];
    const float* b_b   = (const float*)d_in[8];
    float* out = (float*)d_out;

    const int nw    = in_sizes[1];
    const int ml    = in_sizes[0] / nw;
    const int vocab = in_sizes[2] / EMBD;

    size_t sortNeed = (size_t)(100 + nw) * 4;
    size_t embOff   = (sortNeed + 255) & ~(size_t)255;
    size_t embBytes = (size_t)vocab * 64 * 2;
    size_t wOff     = (embOff + embBytes + 1023) & ~(size_t)1023;
    size_t need     = wOff + 131072;

    int* ws = (int*)d_ws;
    bool haveSort = ws_size >= sortNeed;
    if (haveSort) {
        zero_counts_kernel<<<1, 128, 0, stream>>>(ws);
        hist_kernel<<<(nw + 255) / 256, 256, 0, stream>>>(lens, ws, nw);
        prefix_kernel<<<1, 1, 0, stream>>>(ws);
        scatter_kernel<<<(nw + 255) / 256, 256, 0, stream>>>(lens, ws, nw);
    }

    if (ws_size >= need && haveSort) {
        unsigned short* embp = (unsigned short*)((char*)d_ws + embOff);
        unsigned short* wpk  = (unsigned short*)((char*)d_ws + wOff);
        pack_emb_kernel<<<(vocab * 64 + 255) / 256, 256, 0, stream>>>(emb, embp, vocab);
        pack_w_kernel<<<256, 256, 0, stream>>>(Wih_f, Whh_f, b_f, Wih_b, Whh_b, b_b, wpk);
        dim3 grid((nw + 63) / 64, 2);
        bilstm_mfma_kernel<<<grid, BLK, 0, stream>>>(chars, lens, ws + 100, embp, wpk,
                                                     out, nw, ml);
    } else {
        dim3 grid((nw + BLK - 1) / BLK, 2);
        bilstm_fallback_kernel<<<grid, BLK, 0, stream>>>(chars, lens, emb,
                                                         Wih_f, Whh_f, b_f,
                                                         Wih_b, Whh_b, b_b,
                                                         haveSort ? ws + 100 : nullptr,
                                                         out, nw, ml);
    }
}

// Round 12
// 950.564 us; speedup vs baseline: 1.6990x; 1.0917x over previous
//
#include <hip/hip_runtime.h>

#define EMBD 50
#define HID 50
#define BLK 256
#define NT 13               // gate tiles: 13*16 = 208 rows >= 200 real gates
#define LOG2E 1.44269504f

typedef float f32x4 __attribute__((ext_vector_type(4)));
typedef short short8 __attribute__((ext_vector_type(8)));

__device__ __forceinline__ int imax(int a, int b) { return a > b ? a : b; }
__device__ __forceinline__ int imin(int a, int b) { return a < b ? a : b; }

__device__ __forceinline__ unsigned short f2bf(float f) {
    unsigned u = __float_as_uint(f);
    u += 0x7FFFu + ((u >> 16) & 1u);
    return (unsigned short)(u >> 16);
}
// Gate inputs arrive PRESCALED: sigmoid args by log2e, tanh args by 2*log2e.
__device__ __forceinline__ float s2f(float x) {       // sigmoid(g), x = g*log2e
    return __fdividef(1.0f, 1.0f + exp2f(-x));
}
__device__ __forceinline__ float t2f(float x) {       // tanh(g), x = g*2*log2e
    return 1.0f - __fdividef(2.0f, exp2f(x) + 1.0f);
}
__device__ __forceinline__ float tanhrt(float c) {    // tanh of runtime value
    return 1.0f - __fdividef(2.0f, exp2f((2.0f * LOG2E) * c) + 1.0f);
}
// (fallback only)
__device__ __forceinline__ float sigm(float x) {
    return __fdividef(1.0f, 1.0f + __expf(-x));
}
__device__ __forceinline__ float tanhfast(float x) {
    float e = __expf(2.0f * x);
    return 1.0f - __fdividef(2.0f, e + 1.0f);
}

// ---------------- length bucket sort ----------------
// ws ints: [0,25) counts, [25,50) bases, [50,75) cursors, [100,100+NW) perm
__global__ void zero_counts_kernel(int* ws) {
    if (threadIdx.x < 75) ws[threadIdx.x] = 0;
}
__global__ void hist_kernel(const int* __restrict__ lengths, int* ws, int nw) {
    int i = blockIdx.x * blockDim.x + threadIdx.x;
    if (i < nw) atomicAdd(&ws[lengths[i]], 1);
}
__global__ void prefix_kernel(int* ws) {
    if (threadIdx.x == 0 && blockIdx.x == 0) {
        int acc = 0;
        for (int l = 0; l <= 24; ++l) { ws[25 + l] = acc; acc += ws[l]; }
    }
}
__global__ void scatter_kernel(const int* __restrict__ lengths, int* ws, int nw) {
    int i = blockIdx.x * blockDim.x + threadIdx.x;
    if (i < nw) {
        int l = lengths[i];
        int pos = ws[25 + l] + atomicAdd(&ws[50 + l], 1);
        ws[100 + pos] = i;
    }
}

// ---------------- packing kernels ----------------
__global__ void pack_emb_kernel(const float* __restrict__ emb, unsigned short* __restrict__ embp,
                                int vocab) {
    int i = blockIdx.x * blockDim.x + threadIdx.x;
    if (i >= vocab * 64) return;
    int v = i >> 6, e = i & 63;
    float val = (e < EMBD) ? emb[v * EMBD + e] : (e == 63 ? 1.0f : 0.0f);
    embp[i] = f2bf(val);
}

// 13-tile weight pack. Row semantics: tile m, row p (p = s*4+q): gate q,
// j = off(s)+m (pad if m >= cnt(s)). off = {0,13,26,38}, cnt = {13,13,12,12}.
// Col semantics: k<64 -> x-part (e=k; k==63 bias). k>=64 -> h-part: the k-slot
// (half=kc-2, group s2, pos r) holds h_{off(s2)+half*8+r} (zero-weight if pad).
// All weights/bias prescaled: i,f,o rows by log2e (sigmoid), g rows by 2*log2e.
__global__ void pack_w_kernel(const float* __restrict__ Wih_f, const float* __restrict__ Whh_f,
                              const float* __restrict__ b_f,
                              const float* __restrict__ Wih_b, const float* __restrict__ Whh_b,
                              const float* __restrict__ b_b,
                              unsigned short* __restrict__ wp) {
    int tid = blockIdx.x * blockDim.x + threadIdx.x;
    if (tid >= 2 * NT * 2048) return;          // 53248
    int i    = tid & 7;
    int lane = (tid >> 3) & 63;
    int kc   = (tid >> 9) & 3;
    int rem  = tid >> 11;
    int m    = rem % NT;
    int dir  = rem / NT;
    const float* Wih = dir ? Wih_b : Wih_f;
    const float* Whh = dir ? Whh_b : Whh_f;
    const float* bv  = dir ? b_b   : b_f;

    int p = lane & 15, grp = lane >> 4;
    int k = kc * 32 + 8 * grp + i;
    int s = p >> 2, q = p & 3;
    int cnt_s = (s < 2) ? 13 : 12;
    float val = 0.0f;
    if (m < cnt_s) {
        int j = 13 * s - (s == 3 ? 1 : 0) + m;
        int row = q * HID + j;
        if (k < 64) {
            if (k < EMBD)      val = Wih[row * EMBD + k];
            else if (k == 63)  val = bv[row];
        } else {
            int kk = k - 64;
            int half = kk >> 5;
            int s2 = (kk >> 3) & 3;
            int r = kk & 7;
            int mcol = half * 8 + r;
            int cnt2 = (s2 < 2) ? 13 : 12;
            if (mcol < cnt2) {
                int jc = 13 * s2 - (s2 == 3 ? 1 : 0) + mcol;
                val = Whh[row * HID + jc];
            }
        }
        val *= (q == 2) ? (2.0f * LOG2E) : LOG2E;
    }
    wp[tid] = f2bf(val);
}

// ---------------- main MFMA kernel ----------------
__device__ __forceinline__ f32x4 mf(const unsigned short* sWl, int m, int kc,
                                    short8 bb, f32x4 acc) {
    const short8 aw = *(const short8*)(sWl + (m * 4 + kc) * 512);
    return __builtin_amdgcn_mfma_f32_16x16x32_bf16(aw, bb, acc, 0, 0, 0);
}

// One j-element per lane per tile: 4 chained MFMAs produce {i,f,g,o} in regs
// 0..3, then the scalar gate update. All state in named registers.
#define TTM(M, C, H) {                                      \
    f32x4 ac = zz;                                          \
    ac = mf(sWl, (M), 0, cx0, ac);                          \
    ac = mf(sWl, (M), 1, cx1, ac);                          \
    ac = mf(sWl, (M), 2, bh0, ac);                          \
    ac = mf(sWl, (M), 3, bh1, ac);                          \
    float cn = s2f(ac[1]) * (C) + s2f(ac[0]) * t2f(ac[2]);  \
    float hn = s2f(ac[3]) * tanhrt(cn);                     \
    (C) = upd ? cn : (C);                                   \
    (H) = upd ? hn : (H); }

__global__ __launch_bounds__(BLK, 2)
void bilstm_mfma_kernel(const int* __restrict__ chars,
                        const int* __restrict__ lengths,
                        const int* __restrict__ perm,
                        const unsigned short* __restrict__ embp,
                        const unsigned short* __restrict__ wp,
                        float* __restrict__ out, int nw, int ml)
{
    const int dir = blockIdx.y;
    __shared__ unsigned short sW[NT * 4 * 512];   // 52 KB of A-fragments
    {
        const float4* src = (const float4*)(wp + dir * (NT * 4 * 512));
        float4* dst = (float4*)sW;
        for (int i = threadIdx.x; i < NT * 4 * 512 / 8; i += BLK) dst[i] = src[i];
    }
    __syncthreads();

    const int lane = threadIdx.x & 63;
    const int wv   = threadIdx.x >> 6;
    const int wcol = lane & 15;          // word column
    const int s    = lane >> 4;          // lane group

    int gidx = (blockIdx.x * 4 + wv) * 16 + wcol;
    gidx = imin(gidx, nw - 1);
    const int word = perm[gidx];
    const int len  = lengths[word];

    int lmax = len;
    lmax = imax(lmax, __shfl_xor(lmax, 1));
    lmax = imax(lmax, __shfl_xor(lmax, 2));
    lmax = imax(lmax, __shfl_xor(lmax, 4));
    lmax = imax(lmax, __shfl_xor(lmax, 8));

    const int* charp = chars + (size_t)word * ml;
    const unsigned short* sWl = sW + lane * 8;

    const f32x4 zz = {0.0f, 0.0f, 0.0f, 0.0f};
    float c00=0,c01=0,c02=0,c03=0,c04=0,c05=0,c06=0,c07=0,c08=0,c09=0,c10=0,c11=0,c12=0;
    float h00=0,h01=0,h02=0,h03=0,h04=0,h05=0,h06=0,h07=0,h08=0,h09=0,h10=0,h11=0,h12=0;
    short8 bh0, bh1;
#pragma unroll
    for (int i2 = 0; i2 < 8; ++i2) { bh0[i2] = 0; bh1[i2] = 0; }

    // prefetch x for t=0
    short8 cx0, cx1;
    if (lmax > 0) {
        int pos0 = dir ? imax(len - 1, 0) : 0;
        int ch = charp[pos0];
        cx0 = *(const short8*)(embp + ch * 64 + 8 * s);
        cx1 = *(const short8*)(embp + ch * 64 + 32 + 8 * s);
    }

    for (int t = 0; t < lmax; ++t) {
        // prefetch next step's x (latency hides under the MFMA blocks)
        int tn = (t + 1 < lmax) ? t + 1 : t;
        int posn = dir ? imax(len - 1 - tn, 0) : tn;
        int chn = charp[posn];
        short8 nx0 = *(const short8*)(embp + chn * 64 + 8 * s);
        short8 nx1 = *(const short8*)(embp + chn * 64 + 32 + 8 * s);

        const bool upd = (t < len);
        // bh0/bh1 hold PREVIOUS h throughout; rebuilt after all tiles.
        TTM(0,  c00, h00)
        TTM(1,  c01, h01)
        TTM(2,  c02, h02)
        TTM(3,  c03, h03)
        TTM(4,  c04, h04)
        TTM(5,  c05, h05)
        TTM(6,  c06, h06)
        TTM(7,  c07, h07)
        TTM(8,  c08, h08)
        TTM(9,  c09, h09)
        TTM(10, c10, h10)
        TTM(11, c11, h11)
        TTM(12, c12, h12)

        // repack h -> bf16 B-fragments (lane-local; bh1[5..7] stay 0: those
        // k-slots have all-zero weight columns)
        bh0[0] = (short)f2bf(h00); bh0[1] = (short)f2bf(h01);
        bh0[2] = (short)f2bf(h02); bh0[3] = (short)f2bf(h03);
        bh0[4] = (short)f2bf(h04); bh0[5] = (short)f2bf(h05);
        bh0[6] = (short)f2bf(h06); bh0[7] = (short)f2bf(h07);
        bh1[0] = (short)f2bf(h08); bh1[1] = (short)f2bf(h09);
        bh1[2] = (short)f2bf(h10); bh1[3] = (short)f2bf(h11);
        bh1[4] = (short)f2bf(h12);

        cx0 = nx0; cx1 = nx1;
    }

    // lane's j range: [off(s), off(s)+cnt(s)), contiguous
    int offs = 13 * s - (s == 3 ? 1 : 0);
    float* outw = out + (size_t)word * (2 * HID) + dir * HID + offs;
    outw[0] = h00; outw[1] = h01; outw[2]  = h02; outw[3]  = h03;
    outw[4] = h04; outw[5] = h05; outw[6]  = h06; outw[7]  = h07;
    outw[8] = h08; outw[9] = h09; outw[10] = h10; outw[11] = h11;
    if (s < 2) outw[12] = h12;   // pad element for s>=2
}

// ---------------- R1 fallback (scalar f32) ----------------
__global__ __launch_bounds__(BLK, 2)
void bilstm_fallback_kernel(const int* __restrict__ chars,
                            const int* __restrict__ lengths,
                            const float* __restrict__ emb,
                            const float* __restrict__ Wih_f, const float* __restrict__ Whh_f, const float* __restrict__ b_f,
                            const float* __restrict__ Wih_b, const float* __restrict__ Whh_b, const float* __restrict__ b_b,
                            const int* __restrict__ perm,
                            float* __restrict__ out, int nw, int ml)
{
    const int dir = blockIdx.y;
    const float* Wih = dir ? Wih_b : Wih_f;
    const float* Whh = dir ? Whh_b : Whh_f;
    const float* bv  = dir ? b_b  : b_f;
    __shared__ float4 sWU4[HID * 100];
    __shared__ float4 sB4[HID];
    {
        float* p = (float*)sWU4;
        for (int i = threadIdx.x; i < HID * 100 * 4; i += BLK) {
            int g = i & 3, r = i >> 2, j = r / 100, k = r - j * 100;
            p[i] = (k < EMBD) ? Wih[(j + g * HID) * EMBD + k]
                              : Whh[(j + g * HID) * HID + (k - EMBD)];
        }
        if (threadIdx.x < HID) {
            int j = threadIdx.x;
            sB4[j] = make_float4(bv[j], bv[j + HID], bv[j + 2*HID], bv[j + 3*HID]);
        }
    }
    __syncthreads();
    int gid = blockIdx.x * BLK + threadIdx.x;
    if (gid >= nw) return;
    int word = perm ? perm[gid] : gid;
    int len  = lengths[word];
    float h[HID], x[EMBD], c[HID], hn[HID];
#pragma unroll
    for (int j = 0; j < HID; ++j) h[j] = 0.f;
#pragma unroll 1
    for (int j = 0; j < HID; ++j) c[j] = 0.f;
    const int* wch = chars + word * ml;
    float* op = out + (size_t)word * (2 * HID) + dir * HID;
#pragma unroll 1
    for (int t = 0; t < len; ++t) {
        int pos = dir ? (len - 1 - t) : t;
        int ch = wch[pos];
        const float2* ep = (const float2*)(emb + ch * EMBD);
#pragma unroll
        for (int k = 0; k < EMBD / 2; ++k) { float2 v = ep[k]; x[2*k] = v.x; x[2*k+1] = v.y; }
#pragma unroll 1
        for (int j = 0; j < HID; ++j) {
            const float4* wpt = sWU4 + j * 100;
            float4 bb = sB4[j];
            float gi = bb.x, gf = bb.y, gg = bb.z, go = bb.w;
#pragma unroll
            for (int k = 0; k < EMBD; ++k) {
                float4 w = wpt[k]; float xv = x[k];
                gi += w.x*xv; gf += w.y*xv; gg += w.z*xv; go += w.w*xv;
            }
#pragma unroll
            for (int k = 0; k < HID; ++k) {
                float4 w = wpt[EMBD + k]; float hv = h[k];
                gi += w.x*hv; gf += w.y*hv; gg += w.z*hv; go += w.w*hv;
            }
            float cn = sigm(gf) * c[j] + sigm(gi) * tanhfast(gg);
            c[j] = cn;
            hn[j] = sigm(go) * tanhfast(cn);
        }
#pragma unroll
        for (int j = 0; j < HID; ++j) h[j] = hn[j];
    }
#pragma unroll
    for (int j = 0; j < HID / 2; ++j)
        ((float2*)op)[j] = make_float2(h[2*j], h[2*j+1]);
}

extern "C" void kernel_launch(void* const* d_in, const int* in_sizes, int n_in,
                              void* d_out, int out_size, void* d_ws, size_t ws_size,
                              hipStream_t stream) {
    const int*   chars = (const int*)  d_in[0];
    const int*   lens  = (const int*)  d_in[1];
    const float* emb   = (const float*)d_in[2];
    const float* Wih_f = (const float*)d_in[3];
    const float* Whh_f = (const float*)d_in[4];
    const float* b_f   = (const float*)d_in[5];
    const float* Wih_b = (const float*)d_in[6];
    const float* Whh_b = (const float*)d_in[7];
    const float* b_b   = (const float*)d_in[8];
    float* out = (float*)d_out;

    const int nw    = in_sizes[1];
    const int ml    = in_sizes[0] / nw;
    const int vocab = in_sizes[2] / EMBD;

    size_t sortNeed = (size_t)(100 + nw) * 4;
    size_t embOff   = (sortNeed + 255) & ~(size_t)255;
    size_t embBytes = (size_t)vocab * 64 * 2;
    size_t wOff     = (embOff + embBytes + 1023) & ~(size_t)1023;
    size_t need     = wOff + (size_t)2 * NT * 2048 * 2;   // 106496 B

    int* ws = (int*)d_ws;
    bool haveSort = ws_size >= sortNeed;
    if (haveSort) {
        zero_counts_kernel<<<1, 128, 0, stream>>>(ws);
        hist_kernel<<<(nw + 255) / 256, 256, 0, stream>>>(lens, ws, nw);
        prefix_kernel<<<1, 1, 0, stream>>>(ws);
        scatter_kernel<<<(nw + 255) / 256, 256, 0, stream>>>(lens, ws, nw);
    }

    if (ws_size >= need && haveSort) {
        unsigned short* embp = (unsigned short*)((char*)d_ws + embOff);
        unsigned short* wpk  = (unsigned short*)((char*)d_ws + wOff);
        pack_emb_kernel<<<(vocab * 64 + 255) / 256, 256, 0, stream>>>(emb, embp, vocab);
        pack_w_kernel<<<(2 * NT * 2048 + 255) / 256, 256, 0, stream>>>(
            Wih_f, Whh_f, b_f, Wih_b, Whh_b, b_b, wpk);
        dim3 grid((nw + 63) / 64, 2);
        bilstm_mfma_kernel<<<grid, BLK, 0, stream>>>(chars, lens, ws + 100, embp, wpk,
                                                     out, nw, ml);
    } else {
        dim3 grid((nw + BLK - 1) / BLK, 2);
        bilstm_fallback_kernel<<<grid, BLK, 0, stream>>>(chars, lens, emb,
                                                         Wih_f, Whh_f, b_f,
                                                         Wih_b, Whh_b, b_b,
                                                         haveSort ? ws + 100 : nullptr,
                                                         out, nw, ml);
    }
}